// Round 11
// baseline (1290.069 us; speedup 1.0000x reference)
//
#include <hip/hip_runtime.h>

// PartialGConv: partial temporal conv (TK=9, pad 4) + mask-ratio + graph einsum.
// FUSED kernel (r9 structure reverted from r10's regression): bf16 implicit-GEMM
// (MFMA 16x16x32, BM=192 x BN=208(8t) x K=576) with LDS A-ring + once-staged B
// window; MFMA (k,v)-contraction epilogue. r11: Pl stride 344 (bank-conflict
// fix), m_bool folded back into the fused epilogue, per-wave iteration stagger.
//
// ws layout (bytes):
//   xmr  u16[32][6656][64]  @0          x*mask bf16 row-major, padded rows
//   wb   u16[192][576]      @27,262,976 weights bf16, k=dt*64+cin, 16B-slot swizzled
//   msum f32[32][6400]      @27,484,160 sum_cin mask
//   s    f32[32][6400]      @28,303,360 576/(upd+eps)*uc^2
//   mr   f32[32][6400]      @29,122,560 mask_ratio
//   mb   f32[32][6400]      @29,941,760 m_bool
//   Bc   f32[32][3][256][25]@30,760,960 sum_v uc*A[k,v,w]

typedef unsigned short u16;
typedef unsigned int u32;
typedef short short8 __attribute__((ext_vector_type(8)));
typedef float f32x4 __attribute__((ext_vector_type(4)));

#define TV 6400
#define KC 192
#define KDIM 576
#define NPADT 6656          // 100 front pad + 6400 + 156 back pad
#define Y_SIZE 13107200
#define MB_OFF 13109075     // Y_SIZE + 1875

#define OFF_WB   27262976
#define OFF_MSUM 27484160
#define OFF_S    28303360
#define OFF_MR   29122560
#define OFF_MB   29941760
#define OFF_BC   30760960

// LDS map (63,936 B total).  K-loop: xwin [0,52224) + A-ring [52224,76800)?
// no: A-ring lives at 52224 (2 x 12,288 = 24,576) -> but misc aliases it AFTER
// the loop.  Epilogue aliases: Pl u16[64][344] @0 (44,032 B); Ys f32[32][201] @0;
// misc @52224: Ab 6144 | Bcs 2400 | mrs 800 | bias 768 | ss 800 | mbs 800.
#define L_ARING 52224       // NOTE: ring total = 52224+24576 = 76800 during loop
#define L_AB    52224
#define L_BCS   58368
#define L_MRS   60768
#define L_BIAS  61568
#define L_SS    62336
#define L_MBS   63136

#define VMCNT(N) asm volatile("s_waitcnt vmcnt(" #N ")" ::: "memory")

__device__ __forceinline__ u16 f2bf(float f) {
  u32 u = __builtin_bit_cast(u32, f);
  u = (u + 0x7FFFu + ((u >> 16) & 1u)) >> 16;   // RTNE
  return (u16)u;
}
__device__ __forceinline__ float bf2f(u16 h) {
  return __builtin_bit_cast(float, (u32)h << 16);
}
__device__ __forceinline__ void gload_lds16(const u16* g, u16* l) {
  __builtin_amdgcn_global_load_lds(
      (const __attribute__((address_space(1))) u32*)(const void*)g,
      (__attribute__((address_space(3))) u32*)(void*)l, 16, 0, 0);
}

// ---- zero the temporal pad rows of xmr --------------------------------------
__global__ void k_pad(u16* __restrict__ xmr) {
  int i = blockIdx.x * 256 + threadIdx.x;       // 65536 uint4
  if (i >= 65536) return;
  int n = i >> 11, r = i & 2047;                // 256 pad rows x 8 uint4
  int row = r >> 3, c = r & 7;
  int tvrow = (row < 100) ? row : (6400 + row); // front 0..99 / back 6500..6655
  uint4 z; z.x = z.y = z.z = z.w = 0u;
  *(uint4*)(xmr + ((size_t)n * NPADT + tvrow) * 64 + c * 8) = z;
}

// ---- xmr = bf16(x*mask) row-major [tvp][64] + msum = sum_cin mask ------------
__global__ void k_xmT(const float* __restrict__ x, const float* __restrict__ mask,
                      u16* __restrict__ xmr, float* __restrict__ msum) {
  const int tvb = blockIdx.x, n = blockIdx.y;   // grid (100, 32), block 256
  const int tvl = threadIdx.x & 63, q = threadIdx.x >> 6;  // 4 quads of 16 cin
  const int tv = tvb * 64 + tvl;
  const float* xp = x + ((size_t)n * 64 + q * 16) * TV + tv;
  const float* mp = mask + ((size_t)n * 64 + q * 16) * TV + tv;
  u16 vals[16];
  float msacc = 0.f;
#pragma unroll
  for (int j = 0; j < 16; ++j) {                // coalesced: lanes = consecutive tv
    float xv = xp[(size_t)j * TV];
    float mv = mp[(size_t)j * TV];
    msacc += mv;
    vals[j] = f2bf(xv * mv);
  }
  uint4 lo, hi;
  lo.x = vals[0] | ((u32)vals[1] << 16);  lo.y = vals[2] | ((u32)vals[3] << 16);
  lo.z = vals[4] | ((u32)vals[5] << 16);  lo.w = vals[6] | ((u32)vals[7] << 16);
  hi.x = vals[8] | ((u32)vals[9] << 16);  hi.y = vals[10] | ((u32)vals[11] << 16);
  hi.z = vals[12] | ((u32)vals[13] << 16); hi.w = vals[14] | ((u32)vals[15] << 16);
  u16* dst = xmr + ((size_t)n * NPADT + 100 + tv) * 64 + q * 16;
  *(uint4*)dst = lo;
  *(uint4*)(dst + 8) = hi;
  __shared__ float red[4][64];
  red[q][tvl] = msacc;
  __syncthreads();
  if (q == 0) msum[n * TV + tv] = red[0][tvl] + red[1][tvl] + red[2][tvl] + red[3][tvl];
}

// ---- wb[kc][k=dt*64+cin], bf16, 16B-slot XOR pre-swizzle (by (kc>>1)&3) -----
__global__ void k_w(const float* __restrict__ weight, u16* __restrict__ wb) {
  int i = blockIdx.x * 256 + threadIdx.x;      // 110592
  if (i >= 110592) return;
  int kc = i / KDIM, k = i % KDIM;
  int cin = k & 63, dt = k >> 6;
  float v = weight[(kc * 64 + cin) * 9 + dt];
  int phys = (k & ~31) | ((((k >> 3) & 3) ^ ((kc >> 1) & 3)) << 3) | (k & 7);
  wb[kc * KDIM + phys] = f2bf(v);
}

// ---- per (n,t): upd -> s, mask_ratio, m_bool, Bc ----------------------------
__global__ void k_prep(const float* __restrict__ msum, const float* __restrict__ A_g,
                       float* __restrict__ s_ws, float* __restrict__ mr_ws,
                       float* __restrict__ mb_ws, float* __restrict__ Bc_ws) {
  int b = blockIdx.x;                          // 8192 = n*256 + t
  int n = b >> 8, t = b & 255;
  int tid = threadIdx.x;                       // 64
  __shared__ float uc[25];
  if (tid < 25) {
    float upd = 0.f;
    for (int dt = 0; dt < 9; ++dt) {
      int tt = t + dt - 4;
      if (tt >= 0 && tt < 256) upd += msum[n * TV + tt * 25 + tid];
    }
    float u_c = fminf(fmaxf(upd, 0.f), 1.f);
    float ratio = 576.f / (upd + 1e-8f);
    s_ws[n * TV + t * 25 + tid] = ratio * u_c * u_c;  // coeff of raw in out
    uc[tid] = u_c;
  }
  __syncthreads();
  if (tid < 25) {
    int w = tid;
    float M = 0.f;
    for (int k = 0; k < 3; ++k) {
      float acc = 0.f;
      for (int v = 0; v < 25; ++v) acc += uc[v] * A_g[(k * 25 + v) * 25 + w];
      Bc_ws[((size_t)(n * 3 + k) * 256 + t) * 25 + w] = acc;
      M += acc;
    }
    float mbv = (M != 0.f) ? 1.f : 0.f;
    mr_ws[n * TV + t * 25 + w] = mbv / (M + 1e-8f);
    mb_ws[n * TV + t * 25 + w] = mbv;
  }
}

// ---- FUSED: implicit-GEMM + MFMA (k,v)-contraction + coalesced epilogue -----
// Block (tg, n): 1024 threads, 16 waves = 4(M) x 4(N). Wave cols: wn<3 -> 4
// frags (64 cols), wn=3 -> 1 frag (cols 192-207; 200-207 dead, guarded).
// K-loop: LDS A-ring (2 bufs), one VMCNT(0)+barrier per step (r9 proven).
__global__ __launch_bounds__(1024, 4) void k_fused(
    const u16* __restrict__ xmr, const u16* __restrict__ wb,
    const float* __restrict__ s_g, const float* __restrict__ A_g,
    const float* __restrict__ Bc_g, const float* __restrict__ mr_g,
    const float* __restrict__ mb_g, const float* __restrict__ bias_g,
    float* __restrict__ out) {
  __shared__ __align__(16) char ring[76800];

  const int tid = threadIdx.x;
  const int tg = blockIdx.x;                  // 0..31 (8-t group)
  const int n = blockIdx.y;                   // 0..31
  const int tv0 = tg * 200;
  const int lane = tid & 63, wid = tid >> 6;
  const int wm = wid >> 2, wn = wid & 3;
  const int lrow = lane & 15, lgrp = lane >> 4;
  const int nf = (wn == 3) ? 1 : 4, colb = wn * 64;

  const u16* xmn = xmr + (size_t)n * NPADT * 64;
  u16* xwin = (u16*)(ring);

  f32x4 acc[3][4] = {};

  // ---- prologue: stage whole B window (51 loads) + A step 0 (12 loads) ------
  {
    // window rows [tv0, tv0+408) padded; tv0 % 8 == 0 -> swizzle key invariant
    const int srow_g = lane >> 3, sl = (lane & 7) ^ (lane >> 3);  // per-lane
    for (int t = wid; t < 51; t += 16) {
      const u16* src = xmn + ((size_t)(tv0 + t * 8 + srow_g) * 64 + sl * 8);
      gload_lds16(src, xwin + t * 512);
    }
    if (wid < 12) {
      u16* abase = (u16*)(ring + L_ARING);
      const u16* src = wb + (size_t)(wid * 16 + (lane >> 2)) * KDIM + (lane & 3) * 8;
      gload_lds16(src, abase + wid * 512);
    }
  }
  VMCNT(0);
  __builtin_amdgcn_s_barrier();
  asm volatile("" ::: "memory");

  // ---- K-loop: 18 steps; only A staged per step ----------------------------
  for (int ks = 0; ks < 18; ++ks) {
    const int cur = ks & 1;
    if (ks < 17 && wid < 12) {                 // stage A(ks+1) into buf cur^1
      u16* abase = (u16*)(ring + L_ARING + (cur ^ 1) * 12288);
      const u16* src = wb + (size_t)(wid * 16 + (lane >> 2)) * KDIM + (ks + 1) * 32 + (lane & 3) * 8;
      gload_lds16(src, abase + wid * 512);
    }

    const u16* abuf = (const u16*)(ring + L_ARING + cur * 12288);
    short8 af[3];
#pragma unroll
    for (int m = 0; m < 3; ++m) {
      int arow = wm * 48 + m * 16 + lrow;
      af[m] = *(const short8*)&abuf[arow * 32 + ((lgrp ^ ((arow >> 1) & 3)) << 3)];
    }
    const int dt = ks >> 1;
    const int rbase = 100 + (dt - 4) * 25 + colb + lrow;   // xwin row for ct=0
    const int slb = (ks & 1) * 4 + lgrp;                   // logical 16B slot
#pragma unroll
    for (int ct2 = 0; ct2 < 4; ++ct2) {
      int ct = (ct2 + wn) & 3;                 // stagger: de-convoy LDS bursts
      if (ct < nf) {
        int srow = rbase + ct * 16;
        short8 bfr = *(const short8*)&xwin[srow * 64 + ((slb ^ (srow & 7)) << 3)];
#pragma unroll
        for (int m2 = 0; m2 < 3; ++m2) {
          int m = (m2 + wm) % 3;
          acc[m][ct] = __builtin_amdgcn_mfma_f32_16x16x32_bf16(af[m], bfr, acc[m][ct], 0, 0, 0);
        }
      }
    }

    if (ks < 17) {
      VMCNT(0);                        // own A(ks+1) load landed (overlap=compute)
      __builtin_amdgcn_s_barrier();    // all waves done reading abuf[cur]
      asm volatile("" ::: "memory");
    }
  }

  // ---- epilogue setup: zero Pl, stage Ab/Bcs/mrs/bias/ss/mbs ---------------
  __syncthreads();                     // all xwin/abuf reads done; safe to alias
  u16*   Plu   = (u16*)ring;           // [64][344]: tcol = t*40+v, pads zero
  u16*   Abu   = (u16*)(ring + L_AB);  // [3k][2nt][16w][32v] bf16 B-frag layout
  float* Bcsf  = (float*)(ring + L_BCS);
  float* mrsf  = (float*)(ring + L_MRS);
  float* biasf = (float*)(ring + L_BIAS);
  float* ssf   = (float*)(ring + L_SS);
  float* mbsf  = (float*)(ring + L_MBS);
  for (int i = tid; i < 11008; i += 1024) ((u32*)ring)[i] = 0;  // zero Pl (44KB)
  for (int i = tid; i < 3072; i += 1024) {
    int kk = i >> 10, r = i & 1023;
    int nt = r >> 9, rr = r & 511, wl = rr >> 5, v = rr & 31;
    int w = nt * 16 + wl;
    float val = (v < 25 && w < 25) ? A_g[(kk * 25 + v) * 25 + w] : 0.f;
    Abu[i] = f2bf(val);
  }
  if (tid < 600) {
    int k = tid / 200, t = (tid % 200) / 25, w = tid % 25;
    Bcsf[tid] = Bc_g[((size_t)(n * 3 + k) * 256 + tg * 8 + t) * 25 + w];
  }
  if (tid < 200) {
    mrsf[tid] = mr_g[n * TV + tv0 + tid];
    ssf[tid]  = s_g[n * TV + tv0 + tid];
    mbsf[tid] = mb_g[n * TV + tv0 + tid];
  }
  if (tid >= 512 && tid < 704) biasf[tid - 512] = bias_g[tid - 512];
  __syncthreads();

  // ---- MFMA contraction: y(ct,w) = sum_v P(ct,v) * A(v,w), per-k -----------
  f32x4 yacc[2][2] = {};
  for (int k = 0; k < 3; ++k) {
    // stage Pl_k = bf16(acc * s) for rows of this k
#pragma unroll
    for (int m = 0; m < 3; ++m) {
      int R = wm * 48 + m * 16 + lgrp * 4;
      if ((R >> 6) == k) {
        int cb = R & 63;
#pragma unroll
        for (int ct = 0; ct < 4; ++ct) {
          if (ct < nf) {
            int col = colb + ct * 16 + lrow;
            if (col < 200) {
              int t = col / 25, v = col - t * 25;
              float sv = ssf[col];
              int tc = t * 40 + v;
#pragma unroll
              for (int r = 0; r < 4; ++r)
                Plu[(cb + r) * 344 + tc] = f2bf(acc[m][ct][r] * sv);
            }
          }
        }
      }
    }
    __syncthreads();
    // contraction MFMAs: wave owns M-tiles {wid*2, wid*2+1}
    short8 pb[2];
#pragma unroll
    for (int nt = 0; nt < 2; ++nt)
      pb[nt] = *(const short8*)&Abu[((k * 2 + nt) * 16 + lrow) * 32 + lgrp * 8];
#pragma unroll
    for (int mi = 0; mi < 2; ++mi) {
      int mt = wid * 2 + mi;
      const short8 pa = *(const short8*)
          &Plu[(mt * 2 + (lrow >> 3)) * 344 + (lrow & 7) * 40 + lgrp * 8];
#pragma unroll
      for (int nt = 0; nt < 2; ++nt)
        yacc[mi][nt] = __builtin_amdgcn_mfma_f32_16x16x32_bf16(pa, pb[nt], yacc[mi][nt], 0, 0, 0);
    }
    __syncthreads();                   // before next k overwrites Pl
  }

  // ---- finalize + transposed coalesced y writes ----------------------------
  // yacc[mi][nt][r]: row ct = (wid*2+mi)*16 + lgrp*4 + r, col w = nt*16 + lrow
  float (*Ysf)[201] = (float(*)[201])ring;     // aliases Pl, barrier-separated
  const size_t base_n = (size_t)(n * 64) * 6400 + tv0;
#pragma unroll
  for (int half = 0; half < 2; ++half) {
    __syncthreads();
    if ((wid >> 3) == half) {
#pragma unroll
      for (int mi = 0; mi < 2; ++mi)
#pragma unroll
        for (int nt = 0; nt < 2; ++nt) {
          int w = nt * 16 + lrow;
          if (w < 25) {
#pragma unroll
            for (int r = 0; r < 4; ++r) {
              int ct = (wid * 2 + mi) * 16 + lgrp * 4 + r;
              int c = ct >> 3, t = ct & 7;
              float bt = biasf[c] * Bcsf[t * 25 + w] +
                         biasf[64 + c] * Bcsf[200 + t * 25 + w] +
                         biasf[128 + c] * Bcsf[400 + t * 25 + w];
              Ysf[c & 31][t * 25 + w] = (yacc[mi][nt][r] + bt) * mrsf[t * 25 + w];
            }
          }
        }
    }
    __syncthreads();
    for (int i = tid; i < 6400; i += 1024) {
      int ch = i / 200, j = i % 200;
      out[base_n + (size_t)(half * 32 + ch) * 6400 + j] = Ysf[ch][j];
    }
  }

  // m_bool: c-independent broadcast, direct coalesced stores
  for (int i = tid; i < 12800; i += 1024) {
    int cc = i / 200, j = i % 200;
    out[MB_OFF + base_n + (size_t)cc * 6400 + j] = mbsf[j];
  }
}

extern "C" void kernel_launch(void* const* d_in, const int* in_sizes, int n_in,
                              void* d_out, int out_size, void* d_ws, size_t ws_size,
                              hipStream_t stream) {
  const float* x      = (const float*)d_in[0];
  const float* A      = (const float*)d_in[1];
  const float* mask   = (const float*)d_in[2];
  const float* weight = (const float*)d_in[3];
  const float* bias   = (const float*)d_in[4];
  float* out = (float*)d_out;
  char* ws = (char*)d_ws;

  u16*   xmr   = (u16*)(ws);
  u16*   wb    = (u16*)(ws + OFF_WB);
  float* msum  = (float*)(ws + OFF_MSUM);
  float* s_ws  = (float*)(ws + OFF_S);
  float* mr_ws = (float*)(ws + OFF_MR);
  float* mb_ws = (float*)(ws + OFF_MB);
  float* Bc_ws = (float*)(ws + OFF_BC);

  k_pad<<<256, 256, 0, stream>>>(xmr);
  k_xmT<<<dim3(100, 32), 256, 0, stream>>>(x, mask, xmr, msum);
  k_w<<<432, 256, 0, stream>>>(weight, wb);
  k_prep<<<8192, 64, 0, stream>>>(msum, A, s_ws, mr_ws, mb_ws, Bc_ws);

  hipMemcpyAsync(out + Y_SIZE, A, 1875 * sizeof(float),
                 hipMemcpyDeviceToDevice, stream);

  k_fused<<<dim3(32, 32), 1024, 0, stream>>>(xmr, wb, s_ws, A, Bc_ws, mr_ws,
                                             mb_ws, bias, out);
}

// Round 12
// 145.701 us; speedup vs baseline: 8.8542x; 8.8542x over previous
//
#include <hip/hip_runtime.h>

// PartialGConv: partial temporal conv (TK=9, pad 4) + mask-ratio + graph einsum.
// FUSED kernel (r9 structure): bf16 implicit-GEMM (MFMA 16x16x32, BM=192 x
// BN=208(8t) x K=576) with LDS A-ring + once-staged B window; MFMA (k,v)-
// contraction epilogue. r12 = r11 minus the runtime-indexed stagger (rule #20
// violation -> acc spilled to scratch, 6 GB traffic). Static indices only.
// Keeps: Pl stride 344 (bank fix), m_bool folded into epilogue.
//
// ws layout (bytes):
//   xmr  u16[32][6656][64]  @0          x*mask bf16 row-major, padded rows
//   wb   u16[192][576]      @27,262,976 weights bf16, k=dt*64+cin, 16B-slot swizzled
//   msum f32[32][6400]      @27,484,160 sum_cin mask
//   s    f32[32][6400]      @28,303,360 576/(upd+eps)*uc^2
//   mr   f32[32][6400]      @29,122,560 mask_ratio
//   mb   f32[32][6400]      @29,941,760 m_bool
//   Bc   f32[32][3][256][25]@30,760,960 sum_v uc*A[k,v,w]

typedef unsigned short u16;
typedef unsigned int u32;
typedef short short8 __attribute__((ext_vector_type(8)));
typedef float f32x4 __attribute__((ext_vector_type(4)));

#define TV 6400
#define KC 192
#define KDIM 576
#define NPADT 6656          // 100 front pad + 6400 + 156 back pad
#define Y_SIZE 13107200
#define MB_OFF 13109075     // Y_SIZE + 1875

#define OFF_WB   27262976
#define OFF_MSUM 27484160
#define OFF_S    28303360
#define OFF_MR   29122560
#define OFF_MB   29941760
#define OFF_BC   30760960

// LDS map. K-loop: xwin [0,52224) + A-ring [52224,76800).
// Epilogue aliases: Pl u16[64][344] @0 (44,032 B); Ys f32[32][201] @0;
// misc @52224: Ab 6144 | Bcs 2400 | mrs 800 | bias 768 | ss 800 | mbs 800.
#define L_ARING 52224
#define L_AB    52224
#define L_BCS   58368
#define L_MRS   60768
#define L_BIAS  61568
#define L_SS    62336
#define L_MBS   63136

#define VMCNT(N) asm volatile("s_waitcnt vmcnt(" #N ")" ::: "memory")

__device__ __forceinline__ u16 f2bf(float f) {
  u32 u = __builtin_bit_cast(u32, f);
  u = (u + 0x7FFFu + ((u >> 16) & 1u)) >> 16;   // RTNE
  return (u16)u;
}
__device__ __forceinline__ float bf2f(u16 h) {
  return __builtin_bit_cast(float, (u32)h << 16);
}
__device__ __forceinline__ void gload_lds16(const u16* g, u16* l) {
  __builtin_amdgcn_global_load_lds(
      (const __attribute__((address_space(1))) u32*)(const void*)g,
      (__attribute__((address_space(3))) u32*)(void*)l, 16, 0, 0);
}

// ---- zero the temporal pad rows of xmr --------------------------------------
__global__ void k_pad(u16* __restrict__ xmr) {
  int i = blockIdx.x * 256 + threadIdx.x;       // 65536 uint4
  if (i >= 65536) return;
  int n = i >> 11, r = i & 2047;                // 256 pad rows x 8 uint4
  int row = r >> 3, c = r & 7;
  int tvrow = (row < 100) ? row : (6400 + row); // front 0..99 / back 6500..6655
  uint4 z; z.x = z.y = z.z = z.w = 0u;
  *(uint4*)(xmr + ((size_t)n * NPADT + tvrow) * 64 + c * 8) = z;
}

// ---- xmr = bf16(x*mask) row-major [tvp][64] + msum = sum_cin mask ------------
__global__ void k_xmT(const float* __restrict__ x, const float* __restrict__ mask,
                      u16* __restrict__ xmr, float* __restrict__ msum) {
  const int tvb = blockIdx.x, n = blockIdx.y;   // grid (100, 32), block 256
  const int tvl = threadIdx.x & 63, q = threadIdx.x >> 6;  // 4 quads of 16 cin
  const int tv = tvb * 64 + tvl;
  const float* xp = x + ((size_t)n * 64 + q * 16) * TV + tv;
  const float* mp = mask + ((size_t)n * 64 + q * 16) * TV + tv;
  u16 vals[16];
  float msacc = 0.f;
#pragma unroll
  for (int j = 0; j < 16; ++j) {                // coalesced: lanes = consecutive tv
    float xv = xp[(size_t)j * TV];
    float mv = mp[(size_t)j * TV];
    msacc += mv;
    vals[j] = f2bf(xv * mv);
  }
  uint4 lo, hi;
  lo.x = vals[0] | ((u32)vals[1] << 16);  lo.y = vals[2] | ((u32)vals[3] << 16);
  lo.z = vals[4] | ((u32)vals[5] << 16);  lo.w = vals[6] | ((u32)vals[7] << 16);
  hi.x = vals[8] | ((u32)vals[9] << 16);  hi.y = vals[10] | ((u32)vals[11] << 16);
  hi.z = vals[12] | ((u32)vals[13] << 16); hi.w = vals[14] | ((u32)vals[15] << 16);
  u16* dst = xmr + ((size_t)n * NPADT + 100 + tv) * 64 + q * 16;
  *(uint4*)dst = lo;
  *(uint4*)(dst + 8) = hi;
  __shared__ float red[4][64];
  red[q][tvl] = msacc;
  __syncthreads();
  if (q == 0) msum[n * TV + tv] = red[0][tvl] + red[1][tvl] + red[2][tvl] + red[3][tvl];
}

// ---- wb[kc][k=dt*64+cin], bf16, 16B-slot XOR pre-swizzle (by (kc>>1)&3) -----
__global__ void k_w(const float* __restrict__ weight, u16* __restrict__ wb) {
  int i = blockIdx.x * 256 + threadIdx.x;      // 110592
  if (i >= 110592) return;
  int kc = i / KDIM, k = i % KDIM;
  int cin = k & 63, dt = k >> 6;
  float v = weight[(kc * 64 + cin) * 9 + dt];
  int phys = (k & ~31) | ((((k >> 3) & 3) ^ ((kc >> 1) & 3)) << 3) | (k & 7);
  wb[kc * KDIM + phys] = f2bf(v);
}

// ---- per (n,t): upd -> s, mask_ratio, m_bool, Bc ----------------------------
__global__ void k_prep(const float* __restrict__ msum, const float* __restrict__ A_g,
                       float* __restrict__ s_ws, float* __restrict__ mr_ws,
                       float* __restrict__ mb_ws, float* __restrict__ Bc_ws) {
  int b = blockIdx.x;                          // 8192 = n*256 + t
  int n = b >> 8, t = b & 255;
  int tid = threadIdx.x;                       // 64
  __shared__ float uc[25];
  if (tid < 25) {
    float upd = 0.f;
    for (int dt = 0; dt < 9; ++dt) {
      int tt = t + dt - 4;
      if (tt >= 0 && tt < 256) upd += msum[n * TV + tt * 25 + tid];
    }
    float u_c = fminf(fmaxf(upd, 0.f), 1.f);
    float ratio = 576.f / (upd + 1e-8f);
    s_ws[n * TV + t * 25 + tid] = ratio * u_c * u_c;  // coeff of raw in out
    uc[tid] = u_c;
  }
  __syncthreads();
  if (tid < 25) {
    int w = tid;
    float M = 0.f;
    for (int k = 0; k < 3; ++k) {
      float acc = 0.f;
      for (int v = 0; v < 25; ++v) acc += uc[v] * A_g[(k * 25 + v) * 25 + w];
      Bc_ws[((size_t)(n * 3 + k) * 256 + t) * 25 + w] = acc;
      M += acc;
    }
    float mbv = (M != 0.f) ? 1.f : 0.f;
    mr_ws[n * TV + t * 25 + w] = mbv / (M + 1e-8f);
    mb_ws[n * TV + t * 25 + w] = mbv;
  }
}

// ---- FUSED: implicit-GEMM + MFMA (k,v)-contraction + coalesced epilogue -----
// Block (tg, n): 1024 threads, 16 waves = 4(M) x 4(N). Wave cols: wn<3 -> 4
// frags (64 cols), wn=3 -> 1 frag (cols 192-207; 200-207 dead, guarded).
// K-loop: LDS A-ring (2 bufs), one VMCNT(0)+barrier per step (r9 proven).
// ALL acc indices compile-time constant (rule #20).
__global__ __launch_bounds__(1024, 4) void k_fused(
    const u16* __restrict__ xmr, const u16* __restrict__ wb,
    const float* __restrict__ s_g, const float* __restrict__ A_g,
    const float* __restrict__ Bc_g, const float* __restrict__ mr_g,
    const float* __restrict__ mb_g, const float* __restrict__ bias_g,
    float* __restrict__ out) {
  __shared__ __align__(16) char ring[76800];

  const int tid = threadIdx.x;
  const int tg = blockIdx.x;                  // 0..31 (8-t group)
  const int n = blockIdx.y;                   // 0..31
  const int tv0 = tg * 200;
  const int lane = tid & 63, wid = tid >> 6;
  const int wm = wid >> 2, wn = wid & 3;
  const int lrow = lane & 15, lgrp = lane >> 4;
  const int nf = (wn == 3) ? 1 : 4, colb = wn * 64;

  const u16* xmn = xmr + (size_t)n * NPADT * 64;
  u16* xwin = (u16*)(ring);

  f32x4 acc[3][4] = {};

  // ---- prologue: stage whole B window (51 loads) + A step 0 (12 loads) ------
  {
    // window rows [tv0, tv0+408) padded; tv0 % 8 == 0 -> swizzle key invariant
    const int srow_g = lane >> 3, sl = (lane & 7) ^ (lane >> 3);  // per-lane
    for (int t = wid; t < 51; t += 16) {
      const u16* src = xmn + ((size_t)(tv0 + t * 8 + srow_g) * 64 + sl * 8);
      gload_lds16(src, xwin + t * 512);
    }
    if (wid < 12) {
      u16* abase = (u16*)(ring + L_ARING);
      const u16* src = wb + (size_t)(wid * 16 + (lane >> 2)) * KDIM + (lane & 3) * 8;
      gload_lds16(src, abase + wid * 512);
    }
  }
  VMCNT(0);
  __builtin_amdgcn_s_barrier();
  asm volatile("" ::: "memory");

  // ---- K-loop: 18 steps; only A staged per step ----------------------------
  for (int ks = 0; ks < 18; ++ks) {
    const int cur = ks & 1;
    if (ks < 17 && wid < 12) {                 // stage A(ks+1) into buf cur^1
      u16* abase = (u16*)(ring + L_ARING + (cur ^ 1) * 12288);
      const u16* src = wb + (size_t)(wid * 16 + (lane >> 2)) * KDIM + (ks + 1) * 32 + (lane & 3) * 8;
      gload_lds16(src, abase + wid * 512);
    }

    const u16* abuf = (const u16*)(ring + L_ARING + cur * 12288);
    short8 af[3];
#pragma unroll
    for (int m = 0; m < 3; ++m) {
      int arow = wm * 48 + m * 16 + lrow;
      af[m] = *(const short8*)&abuf[arow * 32 + ((lgrp ^ ((arow >> 1) & 3)) << 3)];
    }
    const int dt = ks >> 1;
    const int rbase = 100 + (dt - 4) * 25 + colb + lrow;   // xwin row for ct=0
    const int slb = (ks & 1) * 4 + lgrp;                   // logical 16B slot
#pragma unroll
    for (int ct = 0; ct < 4; ++ct) {
      if (ct < nf) {
        int srow = rbase + ct * 16;
        short8 bfr = *(const short8*)&xwin[srow * 64 + ((slb ^ (srow & 7)) << 3)];
#pragma unroll
        for (int m = 0; m < 3; ++m)
          acc[m][ct] = __builtin_amdgcn_mfma_f32_16x16x32_bf16(af[m], bfr, acc[m][ct], 0, 0, 0);
      }
    }

    if (ks < 17) {
      VMCNT(0);                        // own A(ks+1) load landed (overlap=compute)
      __builtin_amdgcn_s_barrier();    // all waves done reading abuf[cur]
      asm volatile("" ::: "memory");
    }
  }

  // ---- epilogue setup: zero Pl, stage Ab/Bcs/mrs/bias/ss/mbs ---------------
  __syncthreads();                     // all xwin/abuf reads done; safe to alias
  u16*   Plu   = (u16*)ring;           // [64][344]: tcol = t*40+v, pads zero
  u16*   Abu   = (u16*)(ring + L_AB);  // [3k][2nt][16w][32v] bf16 B-frag layout
  float* Bcsf  = (float*)(ring + L_BCS);
  float* mrsf  = (float*)(ring + L_MRS);
  float* biasf = (float*)(ring + L_BIAS);
  float* ssf   = (float*)(ring + L_SS);
  float* mbsf  = (float*)(ring + L_MBS);
  for (int i = tid; i < 11008; i += 1024) ((u32*)ring)[i] = 0;  // zero Pl (44KB)
  for (int i = tid; i < 3072; i += 1024) {
    int kk = i >> 10, r = i & 1023;
    int nt = r >> 9, rr = r & 511, wl = rr >> 5, v = rr & 31;
    int w = nt * 16 + wl;
    float val = (v < 25 && w < 25) ? A_g[(kk * 25 + v) * 25 + w] : 0.f;
    Abu[i] = f2bf(val);
  }
  if (tid < 600) {
    int k = tid / 200, t = (tid % 200) / 25, w = tid % 25;
    Bcsf[tid] = Bc_g[((size_t)(n * 3 + k) * 256 + tg * 8 + t) * 25 + w];
  }
  if (tid < 200) {
    mrsf[tid] = mr_g[n * TV + tv0 + tid];
    ssf[tid]  = s_g[n * TV + tv0 + tid];
    mbsf[tid] = mb_g[n * TV + tv0 + tid];
  }
  if (tid >= 512 && tid < 704) biasf[tid - 512] = bias_g[tid - 512];
  __syncthreads();

  // ---- MFMA contraction: y(ct,w) = sum_v P(ct,v) * A(v,w), per-k -----------
  f32x4 yacc[2][2] = {};
  for (int k = 0; k < 3; ++k) {
    // stage Pl_k = bf16(acc * s) for rows of this k
#pragma unroll
    for (int m = 0; m < 3; ++m) {
      int R = wm * 48 + m * 16 + lgrp * 4;
      if ((R >> 6) == k) {
        int cb = R & 63;
#pragma unroll
        for (int ct = 0; ct < 4; ++ct) {
          if (ct < nf) {
            int col = colb + ct * 16 + lrow;
            if (col < 200) {
              int t = col / 25, v = col - t * 25;
              float sv = ssf[col];
              int tc = t * 40 + v;
#pragma unroll
              for (int r = 0; r < 4; ++r)
                Plu[(cb + r) * 344 + tc] = f2bf(acc[m][ct][r] * sv);
            }
          }
        }
      }
    }
    __syncthreads();
    // contraction MFMAs: wave owns M-tiles {wid*2, wid*2+1}
    short8 pb[2];
#pragma unroll
    for (int nt = 0; nt < 2; ++nt)
      pb[nt] = *(const short8*)&Abu[((k * 2 + nt) * 16 + lrow) * 32 + lgrp * 8];
#pragma unroll
    for (int mi = 0; mi < 2; ++mi) {
      int mt = wid * 2 + mi;
      const short8 pa = *(const short8*)
          &Plu[(mt * 2 + (lrow >> 3)) * 344 + (lrow & 7) * 40 + lgrp * 8];
#pragma unroll
      for (int nt = 0; nt < 2; ++nt)
        yacc[mi][nt] = __builtin_amdgcn_mfma_f32_16x16x32_bf16(pa, pb[nt], yacc[mi][nt], 0, 0, 0);
    }
    __syncthreads();                   // before next k overwrites Pl
  }

  // ---- finalize + transposed coalesced y writes ----------------------------
  // yacc[mi][nt][r]: row ct = (wid*2+mi)*16 + lgrp*4 + r, col w = nt*16 + lrow
  float (*Ysf)[201] = (float(*)[201])ring;     // aliases Pl, barrier-separated
  const size_t base_n = (size_t)(n * 64) * 6400 + tv0;
#pragma unroll
  for (int half = 0; half < 2; ++half) {
    __syncthreads();
    if ((wid >> 3) == half) {
#pragma unroll
      for (int mi = 0; mi < 2; ++mi)
#pragma unroll
        for (int nt = 0; nt < 2; ++nt) {
          int w = nt * 16 + lrow;
          if (w < 25) {
#pragma unroll
            for (int r = 0; r < 4; ++r) {
              int ct = (wid * 2 + mi) * 16 + lgrp * 4 + r;
              int c = ct >> 3, t = ct & 7;
              float bt = biasf[c] * Bcsf[t * 25 + w] +
                         biasf[64 + c] * Bcsf[200 + t * 25 + w] +
                         biasf[128 + c] * Bcsf[400 + t * 25 + w];
              Ysf[c & 31][t * 25 + w] = (yacc[mi][nt][r] + bt) * mrsf[t * 25 + w];
            }
          }
        }
    }
    __syncthreads();
    for (int i = tid; i < 6400; i += 1024) {
      int ch = i / 200, j = i % 200;
      out[base_n + (size_t)(half * 32 + ch) * 6400 + j] = Ysf[ch][j];
    }
  }

  // m_bool: c-independent broadcast, direct coalesced stores
  for (int i = tid; i < 12800; i += 1024) {
    int cc = i / 200, j = i % 200;
    out[MB_OFF + base_n + (size_t)cc * 6400 + j] = mbsf[j];
  }
}

extern "C" void kernel_launch(void* const* d_in, const int* in_sizes, int n_in,
                              void* d_out, int out_size, void* d_ws, size_t ws_size,
                              hipStream_t stream) {
  const float* x      = (const float*)d_in[0];
  const float* A      = (const float*)d_in[1];
  const float* mask   = (const float*)d_in[2];
  const float* weight = (const float*)d_in[3];
  const float* bias   = (const float*)d_in[4];
  float* out = (float*)d_out;
  char* ws = (char*)d_ws;

  u16*   xmr   = (u16*)(ws);
  u16*   wb    = (u16*)(ws + OFF_WB);
  float* msum  = (float*)(ws + OFF_MSUM);
  float* s_ws  = (float*)(ws + OFF_S);
  float* mr_ws = (float*)(ws + OFF_MR);
  float* mb_ws = (float*)(ws + OFF_MB);
  float* Bc_ws = (float*)(ws + OFF_BC);

  k_pad<<<256, 256, 0, stream>>>(xmr);
  k_xmT<<<dim3(100, 32), 256, 0, stream>>>(x, mask, xmr, msum);
  k_w<<<432, 256, 0, stream>>>(weight, wb);
  k_prep<<<8192, 64, 0, stream>>>(msum, A, s_ws, mr_ws, mb_ws, Bc_ws);

  hipMemcpyAsync(out + Y_SIZE, A, 1875 * sizeof(float),
                 hipMemcpyDeviceToDevice, stream);

  k_fused<<<dim3(32, 32), 1024, 0, stream>>>(xmr, wb, s_ws, A, Bc_ws, mr_ws,
                                             mb_ws, bias, out);
}

// Round 13
// 138.222 us; speedup vs baseline: 9.3333x; 1.0541x over previous
//
#include <hip/hip_runtime.h>

// PartialGConv: partial temporal conv (TK=9, pad 4) + mask-ratio + graph einsum.
// FUSED kernel (r12 structure, resized): bf16 implicit-GEMM (MFMA 16x16x32,
// BM=192 x BN=112(4t, 100 useful) x K=576) with LDS A-ring + once-staged B
// window; MFMA (k,v)-contraction epilogue. r13: HALF-SIZE BLOCKS, 512 thr /
// 8 waves, LDS 64.5KB -> 2 blocks/CU = two independent barrier domains per CU
// (one block's barrier stall overlaps the other's compute, m114).
//
// ws layout (bytes):
//   xmr  u16[32][6656][64]  @0          x*mask bf16 row-major, padded rows
//   wb   u16[192][576]      @27,262,976 weights bf16, k=dt*64+cin, 16B-slot swizzled
//   msum f32[32][6400]      @27,484,160 sum_cin mask
//   s    f32[32][6400]      @28,303,360 576/(upd+eps)*uc^2
//   mr   f32[32][6400]      @29,122,560 mask_ratio
//   mb   f32[32][6400]      @29,941,760 m_bool
//   Bc   f32[32][3][256][25]@30,760,960 sum_v uc*A[k,v,w]

typedef unsigned short u16;
typedef unsigned int u32;
typedef short short8 __attribute__((ext_vector_type(8)));
typedef float f32x4 __attribute__((ext_vector_type(4)));

#define TV 6400
#define KC 192
#define KDIM 576
#define NPADT 6656          // 100 front pad + 6400 + 156 back pad
#define Y_SIZE 13107200
#define MB_OFF 13109075     // Y_SIZE + 1875

#define OFF_WB   27262976
#define OFF_MSUM 27484160
#define OFF_S    28303360
#define OFF_MR   29122560
#define OFF_MB   29941760
#define OFF_BC   30760960

// LDS map (64,512 B total). K-loop: xwin [0,39936) = 312 rows x 128B;
// A-ring [39936,64512) = 2 x 12,288.
// Epilogue aliases: Pl u16[64][168] @0 (21,504); Ys f32[32][104] @0 (13,312);
// misc @39936: Ab 6144 | Bcs 1200 | mrs 400 | bias 768 | ss 400 | mbs 400.
#define L_ARING 39936
#define L_AB    39936
#define L_BCS   46080
#define L_MRS   47280
#define L_BIAS  47680
#define L_SS    48448
#define L_MBS   48848

#define VMCNT(N) asm volatile("s_waitcnt vmcnt(" #N ")" ::: "memory")

__device__ __forceinline__ u16 f2bf(float f) {
  u32 u = __builtin_bit_cast(u32, f);
  u = (u + 0x7FFFu + ((u >> 16) & 1u)) >> 16;   // RTNE
  return (u16)u;
}
__device__ __forceinline__ float bf2f(u16 h) {
  return __builtin_bit_cast(float, (u32)h << 16);
}
__device__ __forceinline__ void gload_lds16(const u16* g, u16* l) {
  __builtin_amdgcn_global_load_lds(
      (const __attribute__((address_space(1))) u32*)(const void*)g,
      (__attribute__((address_space(3))) u32*)(void*)l, 16, 0, 0);
}

// ---- zero the temporal pad rows of xmr --------------------------------------
__global__ void k_pad(u16* __restrict__ xmr) {
  int i = blockIdx.x * 256 + threadIdx.x;       // 65536 uint4
  if (i >= 65536) return;
  int n = i >> 11, r = i & 2047;                // 256 pad rows x 8 uint4
  int row = r >> 3, c = r & 7;
  int tvrow = (row < 100) ? row : (6400 + row); // front 0..99 / back 6500..6655
  uint4 z; z.x = z.y = z.z = z.w = 0u;
  *(uint4*)(xmr + ((size_t)n * NPADT + tvrow) * 64 + c * 8) = z;
}

// ---- xmr = bf16(x*mask) row-major [tvp][64] + msum = sum_cin mask ------------
__global__ void k_xmT(const float* __restrict__ x, const float* __restrict__ mask,
                      u16* __restrict__ xmr, float* __restrict__ msum) {
  const int tvb = blockIdx.x, n = blockIdx.y;   // grid (100, 32), block 256
  const int tvl = threadIdx.x & 63, q = threadIdx.x >> 6;  // 4 quads of 16 cin
  const int tv = tvb * 64 + tvl;
  const float* xp = x + ((size_t)n * 64 + q * 16) * TV + tv;
  const float* mp = mask + ((size_t)n * 64 + q * 16) * TV + tv;
  u16 vals[16];
  float msacc = 0.f;
#pragma unroll
  for (int j = 0; j < 16; ++j) {                // coalesced: lanes = consecutive tv
    float xv = xp[(size_t)j * TV];
    float mv = mp[(size_t)j * TV];
    msacc += mv;
    vals[j] = f2bf(xv * mv);
  }
  uint4 lo, hi;
  lo.x = vals[0] | ((u32)vals[1] << 16);  lo.y = vals[2] | ((u32)vals[3] << 16);
  lo.z = vals[4] | ((u32)vals[5] << 16);  lo.w = vals[6] | ((u32)vals[7] << 16);
  hi.x = vals[8] | ((u32)vals[9] << 16);  hi.y = vals[10] | ((u32)vals[11] << 16);
  hi.z = vals[12] | ((u32)vals[13] << 16); hi.w = vals[14] | ((u32)vals[15] << 16);
  u16* dst = xmr + ((size_t)n * NPADT + 100 + tv) * 64 + q * 16;
  *(uint4*)dst = lo;
  *(uint4*)(dst + 8) = hi;
  __shared__ float red[4][64];
  red[q][tvl] = msacc;
  __syncthreads();
  if (q == 0) msum[n * TV + tv] = red[0][tvl] + red[1][tvl] + red[2][tvl] + red[3][tvl];
}

// ---- wb[kc][k=dt*64+cin], bf16, 16B-slot XOR pre-swizzle (by (kc>>1)&3) -----
__global__ void k_w(const float* __restrict__ weight, u16* __restrict__ wb) {
  int i = blockIdx.x * 256 + threadIdx.x;      // 110592
  if (i >= 110592) return;
  int kc = i / KDIM, k = i % KDIM;
  int cin = k & 63, dt = k >> 6;
  float v = weight[(kc * 64 + cin) * 9 + dt];
  int phys = (k & ~31) | ((((k >> 3) & 3) ^ ((kc >> 1) & 3)) << 3) | (k & 7);
  wb[kc * KDIM + phys] = f2bf(v);
}

// ---- per (n,t): upd -> s, mask_ratio, m_bool, Bc ----------------------------
__global__ void k_prep(const float* __restrict__ msum, const float* __restrict__ A_g,
                       float* __restrict__ s_ws, float* __restrict__ mr_ws,
                       float* __restrict__ mb_ws, float* __restrict__ Bc_ws) {
  int b = blockIdx.x;                          // 8192 = n*256 + t
  int n = b >> 8, t = b & 255;
  int tid = threadIdx.x;                       // 64
  __shared__ float uc[25];
  if (tid < 25) {
    float upd = 0.f;
    for (int dt = 0; dt < 9; ++dt) {
      int tt = t + dt - 4;
      if (tt >= 0 && tt < 256) upd += msum[n * TV + tt * 25 + tid];
    }
    float u_c = fminf(fmaxf(upd, 0.f), 1.f);
    float ratio = 576.f / (upd + 1e-8f);
    s_ws[n * TV + t * 25 + tid] = ratio * u_c * u_c;  // coeff of raw in out
    uc[tid] = u_c;
  }
  __syncthreads();
  if (tid < 25) {
    int w = tid;
    float M = 0.f;
    for (int k = 0; k < 3; ++k) {
      float acc = 0.f;
      for (int v = 0; v < 25; ++v) acc += uc[v] * A_g[(k * 25 + v) * 25 + w];
      Bc_ws[((size_t)(n * 3 + k) * 256 + t) * 25 + w] = acc;
      M += acc;
    }
    float mbv = (M != 0.f) ? 1.f : 0.f;
    mr_ws[n * TV + t * 25 + w] = mbv / (M + 1e-8f);
    mb_ws[n * TV + t * 25 + w] = mbv;
  }
}

// ---- FUSED: implicit-GEMM + MFMA (k,v)-contraction + coalesced epilogue -----
// Block (tg, n): 512 threads, 8 waves = 4(M) x 2(N). Wave cols: wn=0 -> 4
// frags (0-63), wn=1 -> 3 frags (64-111; 100-111 dead, guarded at P-stage).
// 2 blocks/CU (64.5KB LDS); one VMCNT(0)+barrier per K-step per block.
__global__ __launch_bounds__(512, 4) void k_fused(
    const u16* __restrict__ xmr, const u16* __restrict__ wb,
    const float* __restrict__ s_g, const float* __restrict__ A_g,
    const float* __restrict__ Bc_g, const float* __restrict__ mr_g,
    const float* __restrict__ mb_g, const float* __restrict__ bias_g,
    float* __restrict__ out) {
  __shared__ __align__(16) char ring[64512];

  const int tid = threadIdx.x;
  const int tg = blockIdx.x;                  // 0..63 (4-t group)
  const int n = blockIdx.y;                   // 0..31
  const int T = tg * 100;                     // useful-tv start (padded coord of tv-100)
  const int lane = tid & 63, wid = tid >> 6;
  const int wm = wid >> 1, wn = wid & 1;
  const int lrow = lane & 15, lgrp = lane >> 4;
  const int nf = 4 - wn, colb = wn * 64;

  const u16* xmn = xmr + (size_t)n * NPADT * 64;
  u16* xwin = (u16*)(ring);

  f32x4 acc[3][4] = {};

  // ---- prologue: stage B window (39 loads, rows [T, T+312)) + A step 0 ------
  {
    // LDS[row][slot] = global[row][slot ^ (row&7)] in WINDOW coords (self-
    // consistent with the read-side XOR regardless of T alignment).
    const int srow_g = lane >> 3, sl = (lane & 7) ^ (lane >> 3);  // per-lane
    for (int t = wid; t < 39; t += 8) {
      const u16* src = xmn + ((size_t)(T + t * 8 + srow_g) * 64 + sl * 8);
      gload_lds16(src, xwin + t * 512);
    }
#pragma unroll
    for (int j = 0; j < 2; ++j) {
      int task = wid + j * 8;
      if (task < 12) {
        u16* abase = (u16*)(ring + L_ARING);
        const u16* src = wb + (size_t)(task * 16 + (lane >> 2)) * KDIM + (lane & 3) * 8;
        gload_lds16(src, abase + task * 512);
      }
    }
  }
  VMCNT(0);
  __builtin_amdgcn_s_barrier();
  asm volatile("" ::: "memory");

  // ---- K-loop: 18 steps; only A staged per step ----------------------------
  for (int ks = 0; ks < 18; ++ks) {
    const int cur = ks & 1;
    if (ks < 17) {                             // stage A(ks+1) into buf cur^1
      u16* abase = (u16*)(ring + L_ARING + (cur ^ 1) * 12288);
#pragma unroll
      for (int j = 0; j < 2; ++j) {
        int task = wid + j * 8;
        if (task < 12) {
          const u16* src = wb + (size_t)(task * 16 + (lane >> 2)) * KDIM + (ks + 1) * 32 + (lane & 3) * 8;
          gload_lds16(src, abase + task * 512);
        }
      }
    }

    const u16* abuf = (const u16*)(ring + L_ARING + cur * 12288);
    short8 af[3];
#pragma unroll
    for (int m = 0; m < 3; ++m) {
      int arow = wm * 48 + m * 16 + lrow;
      af[m] = *(const short8*)&abuf[arow * 32 + ((lgrp ^ ((arow >> 1) & 3)) << 3)];
    }
    const int dt = ks >> 1;
    const int rbase = 100 + (dt - 4) * 25 + colb + lrow;   // window row for ct=0
    const int slb = (ks & 1) * 4 + lgrp;                   // logical 16B slot
#pragma unroll
    for (int ct = 0; ct < 4; ++ct) {
      if (ct < nf) {
        int srow = rbase + ct * 16;
        short8 bfr = *(const short8*)&xwin[srow * 64 + ((slb ^ (srow & 7)) << 3)];
#pragma unroll
        for (int m = 0; m < 3; ++m)
          acc[m][ct] = __builtin_amdgcn_mfma_f32_16x16x32_bf16(af[m], bfr, acc[m][ct], 0, 0, 0);
      }
    }

    if (ks < 17) {
      VMCNT(0);                        // own A(ks+1) loads landed
      __builtin_amdgcn_s_barrier();    // all waves done reading abuf[cur]
      asm volatile("" ::: "memory");
    }
  }

  // ---- epilogue setup: zero Pl, stage Ab/Bcs/mrs/bias/ss/mbs ---------------
  __syncthreads();                     // all xwin/abuf reads done; safe to alias
  u16*   Plu   = (u16*)ring;           // [64][168]: tcol = t*40+v, pads zero
  u16*   Abu   = (u16*)(ring + L_AB);  // [3k][2nt][16w][32v] bf16 B-frag layout
  float* Bcsf  = (float*)(ring + L_BCS);
  float* mrsf  = (float*)(ring + L_MRS);
  float* biasf = (float*)(ring + L_BIAS);
  float* ssf   = (float*)(ring + L_SS);
  float* mbsf  = (float*)(ring + L_MBS);
  for (int i = tid; i < 5376; i += 512) ((u32*)ring)[i] = 0;  // zero Pl (21.5KB)
  for (int i = tid; i < 3072; i += 512) {
    int kk = i >> 10, r = i & 1023;
    int nt = r >> 9, rr = r & 511, wl = rr >> 5, v = rr & 31;
    int w = nt * 16 + wl;
    float val = (v < 25 && w < 25) ? A_g[(kk * 25 + v) * 25 + w] : 0.f;
    Abu[i] = f2bf(val);
  }
  if (tid < 300) {
    int k = tid / 100, t = (tid % 100) / 25, w = tid % 25;
    Bcsf[tid] = Bc_g[((size_t)(n * 3 + k) * 256 + tg * 4 + t) * 25 + w];
  }
  if (tid < 100) {
    mrsf[tid] = mr_g[n * TV + T + tid];
    ssf[tid]  = s_g[n * TV + T + tid];
    mbsf[tid] = mb_g[n * TV + T + tid];
  }
  if (tid >= 256 && tid < 448) biasf[tid - 256] = bias_g[tid - 256];
  __syncthreads();

  // ---- MFMA contraction: y(ct,w) = sum_v P(ct,v) * A(v,w), per-k -----------
  f32x4 yacc[2][2] = {};
  for (int k = 0; k < 3; ++k) {
    // stage Pl_k = bf16(acc * s) for rows of this k
#pragma unroll
    for (int m = 0; m < 3; ++m) {
      int R = wm * 48 + m * 16 + lgrp * 4;
      if ((R >> 6) == k) {
        int cb = R & 63;
#pragma unroll
        for (int ct = 0; ct < 4; ++ct) {
          if (ct < nf) {
            int col = colb + ct * 16 + lrow;
            if (col < 100) {
              int t = col / 25, v = col - t * 25;
              float sv = ssf[col];
              int tc = t * 40 + v;
#pragma unroll
              for (int r = 0; r < 4; ++r)
                Plu[(cb + r) * 168 + tc] = f2bf(acc[m][ct][r] * sv);
            }
          }
        }
      }
    }
    __syncthreads();
    // contraction MFMAs: wave owns M-tiles {wid*2, wid*2+1} (16 tiles of 16 ct)
    short8 pb[2];
#pragma unroll
    for (int nt = 0; nt < 2; ++nt)
      pb[nt] = *(const short8*)&Abu[((k * 2 + nt) * 16 + lrow) * 32 + lgrp * 8];
#pragma unroll
    for (int mi = 0; mi < 2; ++mi) {
      int mt = wid * 2 + mi;
      // A-row = mt*16 + lrow = ct; c = ct>>2 = mt*4 + (lrow>>2), t = lrow&3
      const short8 pa = *(const short8*)
          &Plu[(mt * 4 + (lrow >> 2)) * 168 + (lrow & 3) * 40 + lgrp * 8];
#pragma unroll
      for (int nt = 0; nt < 2; ++nt)
        yacc[mi][nt] = __builtin_amdgcn_mfma_f32_16x16x32_bf16(pa, pb[nt], yacc[mi][nt], 0, 0, 0);
    }
    __syncthreads();                   // before next k overwrites Pl
  }

  // ---- finalize + transposed coalesced y writes ----------------------------
  // yacc[mi][nt][r]: ct = (wid*2+mi)*16 + lgrp*4 + r -> c = wid*8+mi*4+lgrp,
  // t = r; col w = nt*16 + lrow.
  float (*Ysf)[104] = (float(*)[104])ring;     // aliases Pl, barrier-separated
  const size_t base_n = (size_t)(n * 64) * 6400 + T;
#pragma unroll
  for (int half = 0; half < 2; ++half) {
    __syncthreads();
    if ((wid >> 2) == half) {
#pragma unroll
      for (int mi = 0; mi < 2; ++mi) {
        int c = wid * 8 + mi * 4 + lgrp;       // 0..63
#pragma unroll
        for (int nt = 0; nt < 2; ++nt) {
          int w = nt * 16 + lrow;
          if (w < 25) {
#pragma unroll
            for (int r = 0; r < 4; ++r) {
              float bt = biasf[c] * Bcsf[r * 25 + w] +
                         biasf[64 + c] * Bcsf[100 + r * 25 + w] +
                         biasf[128 + c] * Bcsf[200 + r * 25 + w];
              Ysf[c & 31][r * 25 + w] = (yacc[mi][nt][r] + bt) * mrsf[r * 25 + w];
            }
          }
        }
      }
    }
    __syncthreads();
    for (int i = tid; i < 3200; i += 512) {
      int ch = i / 100, j = i % 100;
      out[base_n + (size_t)(half * 32 + ch) * 6400 + j] = Ysf[ch][j];
    }
  }

  // m_bool: c-independent broadcast, direct coalesced stores
  for (int i = tid; i < 6400; i += 512) {
    int cc = i / 100, j = i % 100;
    out[MB_OFF + base_n + (size_t)cc * 6400 + j] = mbsf[j];
  }
}

extern "C" void kernel_launch(void* const* d_in, const int* in_sizes, int n_in,
                              void* d_out, int out_size, void* d_ws, size_t ws_size,
                              hipStream_t stream) {
  const float* x      = (const float*)d_in[0];
  const float* A      = (const float*)d_in[1];
  const float* mask   = (const float*)d_in[2];
  const float* weight = (const float*)d_in[3];
  const float* bias   = (const float*)d_in[4];
  float* out = (float*)d_out;
  char* ws = (char*)d_ws;

  u16*   xmr   = (u16*)(ws);
  u16*   wb    = (u16*)(ws + OFF_WB);
  float* msum  = (float*)(ws + OFF_MSUM);
  float* s_ws  = (float*)(ws + OFF_S);
  float* mr_ws = (float*)(ws + OFF_MR);
  float* mb_ws = (float*)(ws + OFF_MB);
  float* Bc_ws = (float*)(ws + OFF_BC);

  k_pad<<<256, 256, 0, stream>>>(xmr);
  k_xmT<<<dim3(100, 32), 256, 0, stream>>>(x, mask, xmr, msum);
  k_w<<<432, 256, 0, stream>>>(weight, wb);
  k_prep<<<8192, 64, 0, stream>>>(msum, A, s_ws, mr_ws, mb_ws, Bc_ws);

  hipMemcpyAsync(out + Y_SIZE, A, 1875 * sizeof(float),
                 hipMemcpyDeviceToDevice, stream);

  k_fused<<<dim3(64, 32), 512, 0, stream>>>(xmr, wb, s_ws, A, Bc_ws, mr_ws,
                                            mb_ws, bias, out);
}

// Round 14
// 137.475 us; speedup vs baseline: 9.3840x; 1.0054x over previous
//
#include <hip/hip_runtime.h>

// PartialGConv: partial temporal conv (TK=9, pad 4) + mask-ratio + graph einsum.
// FUSED kernel (r13 skeleton): bf16 implicit-GEMM (MFMA 16x16x32, BM=192 x
// BN=112(4t, 100 useful) x K=576), once-staged B window, MFMA contraction
// epilogue, 2 blocks/CU. r14: A-ring deepened to 3 buffers with depth-2
// prefetch and COUNTED per-wave vmcnt (T4) — the per-step VMCNT(0) hard drain
// is gone; loads get ~2 compute phases to land. One barrier per step.
//
// ws layout (bytes):
//   xmr  u16[32][6656][64]  @0          x*mask bf16 row-major, padded rows
//   wb   u16[192][576]      @27,262,976 weights bf16, k=dt*64+cin, 16B-slot swizzled
//   msum f32[32][6400]      @27,484,160 sum_cin mask
//   s    f32[32][6400]      @28,303,360 576/(upd+eps)*uc^2
//   mr   f32[32][6400]      @29,122,560 mask_ratio
//   mb   f32[32][6400]      @29,941,760 m_bool
//   Bc   f32[32][3][256][25]@30,760,960 sum_v uc*A[k,v,w]

typedef unsigned short u16;
typedef unsigned int u32;
typedef short short8 __attribute__((ext_vector_type(8)));
typedef float f32x4 __attribute__((ext_vector_type(4)));

#define TV 6400
#define KC 192
#define KDIM 576
#define NPADT 6656          // 100 front pad + 6400 + 156 back pad
#define Y_SIZE 13107200
#define MB_OFF 13109075     // Y_SIZE + 1875

#define OFF_WB   27262976
#define OFF_MSUM 27484160
#define OFF_S    28303360
#define OFF_MR   29122560
#define OFF_MB   29941760
#define OFF_BC   30760960

// LDS map (76,800 B total = exactly 2 blocks/CU). K-loop: xwin [0,39936) =
// 312 rows x 128B; A-ring [39936,76800) = 3 x 12,288 (ring depth 3).
// Epilogue aliases: Pl u16[64][168] @0 (21,504); Ys f32[32][104] @0;
// misc @39936: Ab 6144 | Bcs 1200 | mrs 400 | bias 768 | ss 400 | mbs 400.
#define L_ARING 39936
#define L_AB    39936
#define L_BCS   46080
#define L_MRS   47280
#define L_BIAS  47680
#define L_SS    48448
#define L_MBS   48848

#define VMCNT(N) asm volatile("s_waitcnt vmcnt(" #N ")" ::: "memory")

__device__ __forceinline__ u16 f2bf(float f) {
  u32 u = __builtin_bit_cast(u32, f);
  u = (u + 0x7FFFu + ((u >> 16) & 1u)) >> 16;   // RTNE
  return (u16)u;
}
__device__ __forceinline__ float bf2f(u16 h) {
  return __builtin_bit_cast(float, (u32)h << 16);
}
__device__ __forceinline__ void gload_lds16(const u16* g, u16* l) {
  __builtin_amdgcn_global_load_lds(
      (const __attribute__((address_space(1))) u32*)(const void*)g,
      (__attribute__((address_space(3))) u32*)(void*)l, 16, 0, 0);
}

// ---- zero the temporal pad rows of xmr --------------------------------------
__global__ void k_pad(u16* __restrict__ xmr) {
  int i = blockIdx.x * 256 + threadIdx.x;       // 65536 uint4
  if (i >= 65536) return;
  int n = i >> 11, r = i & 2047;                // 256 pad rows x 8 uint4
  int row = r >> 3, c = r & 7;
  int tvrow = (row < 100) ? row : (6400 + row); // front 0..99 / back 6500..6655
  uint4 z; z.x = z.y = z.z = z.w = 0u;
  *(uint4*)(xmr + ((size_t)n * NPADT + tvrow) * 64 + c * 8) = z;
}

// ---- xmr = bf16(x*mask) row-major [tvp][64] + msum = sum_cin mask ------------
__global__ void k_xmT(const float* __restrict__ x, const float* __restrict__ mask,
                      u16* __restrict__ xmr, float* __restrict__ msum) {
  const int tvb = blockIdx.x, n = blockIdx.y;   // grid (100, 32), block 256
  const int tvl = threadIdx.x & 63, q = threadIdx.x >> 6;  // 4 quads of 16 cin
  const int tv = tvb * 64 + tvl;
  const float* xp = x + ((size_t)n * 64 + q * 16) * TV + tv;
  const float* mp = mask + ((size_t)n * 64 + q * 16) * TV + tv;
  u16 vals[16];
  float msacc = 0.f;
#pragma unroll
  for (int j = 0; j < 16; ++j) {                // coalesced: lanes = consecutive tv
    float xv = xp[(size_t)j * TV];
    float mv = mp[(size_t)j * TV];
    msacc += mv;
    vals[j] = f2bf(xv * mv);
  }
  uint4 lo, hi;
  lo.x = vals[0] | ((u32)vals[1] << 16);  lo.y = vals[2] | ((u32)vals[3] << 16);
  lo.z = vals[4] | ((u32)vals[5] << 16);  lo.w = vals[6] | ((u32)vals[7] << 16);
  hi.x = vals[8] | ((u32)vals[9] << 16);  hi.y = vals[10] | ((u32)vals[11] << 16);
  hi.z = vals[12] | ((u32)vals[13] << 16); hi.w = vals[14] | ((u32)vals[15] << 16);
  u16* dst = xmr + ((size_t)n * NPADT + 100 + tv) * 64 + q * 16;
  *(uint4*)dst = lo;
  *(uint4*)(dst + 8) = hi;
  __shared__ float red[4][64];
  red[q][tvl] = msacc;
  __syncthreads();
  if (q == 0) msum[n * TV + tv] = red[0][tvl] + red[1][tvl] + red[2][tvl] + red[3][tvl];
}

// ---- wb[kc][k=dt*64+cin], bf16, 16B-slot XOR pre-swizzle (by (kc>>1)&3) -----
__global__ void k_w(const float* __restrict__ weight, u16* __restrict__ wb) {
  int i = blockIdx.x * 256 + threadIdx.x;      // 110592
  if (i >= 110592) return;
  int kc = i / KDIM, k = i % KDIM;
  int cin = k & 63, dt = k >> 6;
  float v = weight[(kc * 64 + cin) * 9 + dt];
  int phys = (k & ~31) | ((((k >> 3) & 3) ^ ((kc >> 1) & 3)) << 3) | (k & 7);
  wb[kc * KDIM + phys] = f2bf(v);
}

// ---- per (n,t): upd -> s, mask_ratio, m_bool, Bc ----------------------------
__global__ void k_prep(const float* __restrict__ msum, const float* __restrict__ A_g,
                       float* __restrict__ s_ws, float* __restrict__ mr_ws,
                       float* __restrict__ mb_ws, float* __restrict__ Bc_ws) {
  int b = blockIdx.x;                          // 8192 = n*256 + t
  int n = b >> 8, t = b & 255;
  int tid = threadIdx.x;                       // 64
  __shared__ float uc[25];
  if (tid < 25) {
    float upd = 0.f;
    for (int dt = 0; dt < 9; ++dt) {
      int tt = t + dt - 4;
      if (tt >= 0 && tt < 256) upd += msum[n * TV + tt * 25 + tid];
    }
    float u_c = fminf(fmaxf(upd, 0.f), 1.f);
    float ratio = 576.f / (upd + 1e-8f);
    s_ws[n * TV + t * 25 + tid] = ratio * u_c * u_c;  // coeff of raw in out
    uc[tid] = u_c;
  }
  __syncthreads();
  if (tid < 25) {
    int w = tid;
    float M = 0.f;
    for (int k = 0; k < 3; ++k) {
      float acc = 0.f;
      for (int v = 0; v < 25; ++v) acc += uc[v] * A_g[(k * 25 + v) * 25 + w];
      Bc_ws[((size_t)(n * 3 + k) * 256 + t) * 25 + w] = acc;
      M += acc;
    }
    float mbv = (M != 0.f) ? 1.f : 0.f;
    mr_ws[n * TV + t * 25 + w] = mbv / (M + 1e-8f);
    mb_ws[n * TV + t * 25 + w] = mbv;
  }
}

// ---- FUSED: implicit-GEMM + MFMA (k,v)-contraction + coalesced epilogue -----
// Block (tg, n): 512 threads, 8 waves = 4(M) x 2(N). Wave cols: wn=0 -> 4
// frags (0-63), wn=1 -> 3 frags (64-111; 100-111 dead, guarded at P-stage).
// 2 blocks/CU; 3-buffer A-ring, depth-2 prefetch, counted vmcnt, 1 barrier/step.
__global__ __launch_bounds__(512, 4) void k_fused(
    const u16* __restrict__ xmr, const u16* __restrict__ wb,
    const float* __restrict__ s_g, const float* __restrict__ A_g,
    const float* __restrict__ Bc_g, const float* __restrict__ mr_g,
    const float* __restrict__ mb_g, const float* __restrict__ bias_g,
    float* __restrict__ out) {
  __shared__ __align__(16) char ring[76800];

  const int tid = threadIdx.x;
  const int tg = blockIdx.x;                  // 0..63 (4-t group)
  const int n = blockIdx.y;                   // 0..31
  const int T = tg * 100;                     // window start (padded coords)
  const int lane = tid & 63, wid = tid >> 6;
  const int wm = wid >> 1, wn = wid & 1;
  const int lrow = lane & 15, lgrp = lane >> 4;
  const int nf = 4 - wn, colb = wn * 64;

  const u16* xmn = xmr + (size_t)n * NPADT * 64;
  u16* xwin = (u16*)(ring);

  f32x4 acc[3][4] = {};

  // A staging helper: 12 tile-loads spread as waves 0-3: 2, waves 4-7: 1.
  auto stageA = [&](int buf, int ks) {
    u16* abase = (u16*)(ring + L_ARING + buf * 12288);
#pragma unroll
    for (int j = 0; j < 2; ++j) {
      int task = wid + j * 8;
      if (task < 12) {
        const u16* src = wb + (size_t)(task * 16 + (lane >> 2)) * KDIM + ks * 32 + (lane & 3) * 8;
        gload_lds16(src, abase + task * 512);
      }
    }
  };

  // ---- prologue: stage B window (39 loads) + A steps 0,1 --------------------
  {
    // LDS[row][slot] = global[row][slot ^ (row&7)] in WINDOW coords.
    const int srow_g = lane >> 3, sl = (lane & 7) ^ (lane >> 3);  // per-lane
    for (int t = wid; t < 39; t += 8) {
      const u16* src = xmn + ((size_t)(T + t * 8 + srow_g) * 64 + sl * 8);
      gload_lds16(src, xwin + t * 512);
    }
    stageA(0, 0);
    stageA(1, 1);
  }
  VMCNT(0);
  __builtin_amdgcn_s_barrier();
  asm volatile("" ::: "memory");

  // ---- K-loop: 18 steps; depth-2 counted-vmcnt pipeline ---------------------
  // Invariant at top of step ks: buf[ks%3] data landed for ALL waves (each
  // wave waited for its own step-ks loads via VMCNT before the prior barrier,
  // and the barrier published them). Staging buf[(ks+2)%3] overwrites
  // buf[(ks-1)%3]: safe — every wave finished its ks-1 ds_reads before the
  // barrier (lgkmcnt before MFMA use, MFMA before barrier in program order).
  for (int ks = 0; ks < 18; ++ks) {
    if (ks < 16) stageA((ks + 2) % 3, ks + 2);

    const u16* abuf = (const u16*)(ring + L_ARING + (ks % 3) * 12288);
    short8 af[3];
#pragma unroll
    for (int m = 0; m < 3; ++m) {
      int arow = wm * 48 + m * 16 + lrow;
      af[m] = *(const short8*)&abuf[arow * 32 + ((lgrp ^ ((arow >> 1) & 3)) << 3)];
    }
    const int dt = ks >> 1;
    const int rbase = 100 + (dt - 4) * 25 + colb + lrow;   // window row for ct=0
    const int slb = (ks & 1) * 4 + lgrp;                   // logical 16B slot
#pragma unroll
    for (int ct = 0; ct < 4; ++ct) {
      if (ct < nf) {
        int srow = rbase + ct * 16;
        short8 bfr = *(const short8*)&xwin[srow * 64 + ((slb ^ (srow & 7)) << 3)];
#pragma unroll
        for (int m = 0; m < 3; ++m)
          acc[m][ct] = __builtin_amdgcn_mfma_f32_16x16x32_bf16(af[m], bfr, acc[m][ct], 0, 0, 0);
      }
    }

    if (ks < 16) {
      // wait for step-(ks+1) loads (issued at ks-1); allow my just-issued
      // step-(ks+2) loads (S of them) to stay in flight.  S: waves 0-3 = 2,
      // waves 4-7 = 1.  vmcnt is wave-uniform (wid is wave-uniform).
      if (wid < 4) VMCNT(2); else VMCNT(1);
      __builtin_amdgcn_s_barrier();
      asm volatile("" ::: "memory");
    } else if (ks == 16) {
      VMCNT(0);                        // last loads (step 17, issued at 15)
      __builtin_amdgcn_s_barrier();
      asm volatile("" ::: "memory");
    }
  }

  // ---- epilogue setup: zero Pl, stage Ab/Bcs/mrs/bias/ss/mbs ---------------
  __syncthreads();                     // all xwin/abuf reads done; safe to alias
  u16*   Plu   = (u16*)ring;           // [64][168]: tcol = t*40+v, pads zero
  u16*   Abu   = (u16*)(ring + L_AB);  // [3k][2nt][16w][32v] bf16 B-frag layout
  float* Bcsf  = (float*)(ring + L_BCS);
  float* mrsf  = (float*)(ring + L_MRS);
  float* biasf = (float*)(ring + L_BIAS);
  float* ssf   = (float*)(ring + L_SS);
  float* mbsf  = (float*)(ring + L_MBS);
  {
    uint4 z; z.x = z.y = z.z = z.w = 0u;
    for (int i = tid; i < 1344; i += 512) ((uint4*)ring)[i] = z;  // zero Pl
  }
  for (int i = tid; i < 3072; i += 512) {
    int kk = i >> 10, r = i & 1023;
    int nt = r >> 9, rr = r & 511, wl = rr >> 5, v = rr & 31;
    int w = nt * 16 + wl;
    float val = (v < 25 && w < 25) ? A_g[(kk * 25 + v) * 25 + w] : 0.f;
    Abu[i] = f2bf(val);
  }
  if (tid < 300) {
    int k = tid / 100, t = (tid % 100) / 25, w = tid % 25;
    Bcsf[tid] = Bc_g[((size_t)(n * 3 + k) * 256 + tg * 4 + t) * 25 + w];
  }
  if (tid < 100) {
    mrsf[tid] = mr_g[n * TV + T + tid];
    ssf[tid]  = s_g[n * TV + T + tid];
    mbsf[tid] = mb_g[n * TV + T + tid];
  }
  if (tid >= 256 && tid < 448) biasf[tid - 256] = bias_g[tid - 256];
  __syncthreads();

  // ---- MFMA contraction: y(ct,w) = sum_v P(ct,v) * A(v,w), per-k -----------
  f32x4 yacc[2][2] = {};
  for (int k = 0; k < 3; ++k) {
    // stage Pl_k = bf16(acc * s) for rows of this k
#pragma unroll
    for (int m = 0; m < 3; ++m) {
      int R = wm * 48 + m * 16 + lgrp * 4;
      if ((R >> 6) == k) {
        int cb = R & 63;
#pragma unroll
        for (int ct = 0; ct < 4; ++ct) {
          if (ct < nf) {
            int col = colb + ct * 16 + lrow;
            if (col < 100) {
              int t = col / 25, v = col - t * 25;
              float sv = ssf[col];
              int tc = t * 40 + v;
#pragma unroll
              for (int r = 0; r < 4; ++r)
                Plu[(cb + r) * 168 + tc] = f2bf(acc[m][ct][r] * sv);
            }
          }
        }
      }
    }
    __syncthreads();
    // contraction MFMAs: wave owns M-tiles {wid*2, wid*2+1} (16 tiles of 16 ct)
    short8 pb[2];
#pragma unroll
    for (int nt = 0; nt < 2; ++nt)
      pb[nt] = *(const short8*)&Abu[((k * 2 + nt) * 16 + lrow) * 32 + lgrp * 8];
#pragma unroll
    for (int mi = 0; mi < 2; ++mi) {
      int mt = wid * 2 + mi;
      // A-row = mt*16 + lrow = ct; c = mt*4 + (lrow>>2), t = lrow&3
      const short8 pa = *(const short8*)
          &Plu[(mt * 4 + (lrow >> 2)) * 168 + (lrow & 3) * 40 + lgrp * 8];
#pragma unroll
      for (int nt = 0; nt < 2; ++nt)
        yacc[mi][nt] = __builtin_amdgcn_mfma_f32_16x16x32_bf16(pa, pb[nt], yacc[mi][nt], 0, 0, 0);
    }
    __syncthreads();                   // before next k overwrites Pl
  }

  // ---- finalize + transposed coalesced y writes ----------------------------
  // yacc[mi][nt][r]: ct = (wid*2+mi)*16 + lgrp*4 + r -> c = wid*8+mi*4+lgrp,
  // t = r; col w = nt*16 + lrow.
  float (*Ysf)[104] = (float(*)[104])ring;     // aliases Pl, barrier-separated
  const size_t base_n = (size_t)(n * 64) * 6400 + T;
#pragma unroll
  for (int half = 0; half < 2; ++half) {
    __syncthreads();
    if ((wid >> 2) == half) {
#pragma unroll
      for (int mi = 0; mi < 2; ++mi) {
        int c = wid * 8 + mi * 4 + lgrp;       // 0..63
#pragma unroll
        for (int nt = 0; nt < 2; ++nt) {
          int w = nt * 16 + lrow;
          if (w < 25) {
#pragma unroll
            for (int r = 0; r < 4; ++r) {
              float bt = biasf[c] * Bcsf[r * 25 + w] +
                         biasf[64 + c] * Bcsf[100 + r * 25 + w] +
                         biasf[128 + c] * Bcsf[200 + r * 25 + w];
              Ysf[c & 31][r * 25 + w] = (yacc[mi][nt][r] + bt) * mrsf[r * 25 + w];
            }
          }
        }
      }
    }
    __syncthreads();
    for (int i = tid; i < 3200; i += 512) {
      int ch = i / 100, j = i % 100;
      out[base_n + (size_t)(half * 32 + ch) * 6400 + j] = Ysf[ch][j];
    }
  }

  // m_bool: c-independent broadcast, direct coalesced stores
  for (int i = tid; i < 6400; i += 512) {
    int cc = i / 100, j = i % 100;
    out[MB_OFF + base_n + (size_t)cc * 6400 + j] = mbsf[j];
  }
}

extern "C" void kernel_launch(void* const* d_in, const int* in_sizes, int n_in,
                              void* d_out, int out_size, void* d_ws, size_t ws_size,
                              hipStream_t stream) {
  const float* x      = (const float*)d_in[0];
  const float* A      = (const float*)d_in[1];
  const float* mask   = (const float*)d_in[2];
  const float* weight = (const float*)d_in[3];
  const float* bias   = (const float*)d_in[4];
  float* out = (float*)d_out;
  char* ws = (char*)d_ws;

  u16*   xmr   = (u16*)(ws);
  u16*   wb    = (u16*)(ws + OFF_WB);
  float* msum  = (float*)(ws + OFF_MSUM);
  float* s_ws  = (float*)(ws + OFF_S);
  float* mr_ws = (float*)(ws + OFF_MR);
  float* mb_ws = (float*)(ws + OFF_MB);
  float* Bc_ws = (float*)(ws + OFF_BC);

  k_pad<<<256, 256, 0, stream>>>(xmr);
  k_xmT<<<dim3(100, 32), 256, 0, stream>>>(x, mask, xmr, msum);
  k_w<<<432, 256, 0, stream>>>(weight, wb);
  k_prep<<<8192, 64, 0, stream>>>(msum, A, s_ws, mr_ws, mb_ws, Bc_ws);

  hipMemcpyAsync(out + Y_SIZE, A, 1875 * sizeof(float),
                 hipMemcpyDeviceToDevice, stream);

  k_fused<<<dim3(64, 32), 512, 0, stream>>>(xmr, wb, s_ws, A, Bc_ws, mr_ws,
                                            mb_ws, bias, out);
}